// Round 4
// baseline (739.971 us; speedup 1.0000x reference)
//
#include <hip/hip_runtime.h>
#include <hip/hip_bf16.h>
#include <stdint.h>

// ConvNACCell: out[n,co,h,w] = sum_{ci,kh,kw} x[n,ci,h+kh-1,w+kw-1] * W[co,ci,kh,kw]
// W = tanh(W_hat)*sigmoid(M_hat). Implicit GEMM, mfma_f32_16x16x32_bf16, fp32 acc.
// Single pass. Block = 128co x 32h x 64w, 16 chunks of 2 rows, 6-slot LDS row
// ring, software pipeline: issue loads (top) -> compute -> pack+ds_write ->
// barrier -> store. 512 blocks = 2/CU, all co-resident.

#define CH_IN  64
#define CH_OUT 128
#define HW     256

typedef __attribute__((ext_vector_type(8))) short short8;   // 8 bf16 = 4 VGPR
typedef __attribute__((ext_vector_type(4))) float f32x4;

// RNE fp32 -> bf16 pair packed into u32 (lo = a, hi = b). Inputs finite.
static __device__ __forceinline__ uint32_t pack_bf16(float a, float b) {
    uint32_t ua = __builtin_bit_cast(uint32_t, a);
    uint32_t ub = __builtin_bit_cast(uint32_t, b);
    ua = (ua + 0x7FFFu + ((ua >> 16) & 1u)) >> 16;
    ub = (ub + 0x7FFFu + ((ub >> 16) & 1u));
    return (ua & 0xFFFFu) | (ub & 0xFFFF0000u);
}

static __device__ __forceinline__ uint4 pack8(const float* v) {
    uint4 w;
    w.x = pack_bf16(v[0], v[1]); w.y = pack_bf16(v[2], v[3]);
    w.z = pack_bf16(v[4], v[5]); w.w = pack_bf16(v[6], v[7]);
    return w;
}

// ---------------------------------------------------------------------------
// Prep: W = tanh(W_hat)*sigmoid(M_hat) as bf16 A-fragments.
//   frag[t][ms][s][lane] (16B): elem j = A[co = ms*16 + (lane&15)]
//                                        [ci = s*32 + (lane>>4)*8 + j], tap t.
// ---------------------------------------------------------------------------
__global__ void __launch_bounds__(256) nac_prep(const float* __restrict__ Wh,
                                                const float* __restrict__ Mh,
                                                uint32_t* __restrict__ Af) {
    int f = blockIdx.x * 256 + threadIdx.x;   // 0..9215
    if (f >= 9 * 8 * 2 * 64) return;
    int lane = f & 63;
    int s    = (f >> 6) & 1;
    int ms   = (f >> 7) & 7;
    int t    = f >> 10;
    int co   = ms * 16 + (lane & 15);
    int ci0  = s * 32 + ((lane >> 4) << 3);

    uint32_t pk[4];
#pragma unroll
    for (int j2 = 0; j2 < 4; ++j2) {
        int ci = ci0 + 2 * j2;
        int k0 = ci * 9 + t;
        int k1 = k0 + 9;
        float w0 = tanhf(Wh[co * 576 + k0]);
        float m0 = Mh[co * 576 + k0];
        float w1 = tanhf(Wh[co * 576 + k1]);
        float m1 = Mh[co * 576 + k1];
        float v0 = w0 * (1.0f / (1.0f + expf(-m0)));
        float v1 = w1 * (1.0f / (1.0f + expf(-m1)));
        pk[j2] = pack_bf16(v0, v1);
    }
    int fragidx = ((t * 8 + ms) * 2 + s) * 64 + lane;
    reinterpret_cast<uint4*>(Af)[fragidx] = make_uint4(pk[0], pk[1], pk[2], pk[3]);
}

// ---------------------------------------------------------------------------
// Conv. LDS ring: 6 slots x 66 px x 8 granules x 16B. Granule (slot,px,g)
// holds bf16 of ci = g'*8..g'*8+7 at pixel px where stored position
// g = g' ^ (px&7) (XOR swizzle; uniform 8 lanes/bank-group on b128 reads).
// Staged local row L (=r_in+1, r_in relative input row): slot = L % 6,
// hh = h0 + L - 1. Chunk c computes output rows 2c,2c+1 (reads L=2c..2c+3),
// stages L=2c+4,2c+5 (slot pair never wraps: base always even).
// ---------------------------------------------------------------------------
#define SLOT_B 8448            // 528 granules * 16B per slot

__global__ void __launch_bounds__(256, 2)
nac_conv(const float* __restrict__ x, const uint32_t* __restrict__ Af,
         float* __restrict__ out) {
    __shared__ __align__(16) uint32_t xl[6 * 528 * 4];   // 50,688 B

    // Bijective XCD-chunked swizzle: 512 blocks, 64 per XCD chunk.
    unsigned bid = blockIdx.x;
    unsigned idx = (bid & 7u) * 64u + (bid >> 3);
    int ht = idx & 7;            // 8 tiles of 32 rows
    int wt = (idx >> 3) & 3;     // 4 tiles of 64 cols
    int n  = idx >> 5;           // batch
    int h0 = ht * 32;
    int w0 = wt * 64;

    const int tid  = threadIdx.x;
    const int lane = tid & 63;
    const int g    = tid & 7;
    const int ci0  = g * 8;
    const int wv   = tid >> 6;
    const int wm   = wv >> 1;    // co half
    const int wn   = wv & 1;     // output row within chunk
    const int col  = lane & 15;
    const int row4 = lane >> 4;

    const float* xn = x + (size_t)n * CH_IN * HW * HW;
    char* lb = reinterpret_cast<char*>(xl);

    // ---- staging geometry (chunk-invariant). Stage region = 2 rows x 66 px
    // x 8 g = 1056 granules; thread covers gi=0..3 (j = gi*256+tid) + tail
    // (tid<32, j = 1024+tid). j -> row = j>=528, jr = j-528*row, px = jr>>3.
    int spx[4], srow[4];
    spx[0] = tid >> 3;                               srow[0] = 0;
    spx[1] = 32 + (tid >> 3);                        srow[1] = 0;
    spx[2] = (tid >= 16) ? ((tid - 16) >> 3) : (64 + (tid >> 3));
    srow[2] = (tid >= 16) ? 1 : 0;
    spx[3] = 30 + (tid >> 3);                        srow[3] = 1;
    const int tpx = 62 + (tid >> 3);                 // tail, row 1

    int dgr[4];     // ds-write granule offset within the 2-row stage region
    int xcol[4];    // clamped global col
    bool wval[4];
#pragma unroll
    for (int gi = 0; gi < 4; ++gi) {
        dgr[gi]  = srow[gi] * 528 + spx[gi] * 8 + (g ^ (spx[gi] & 7));
        int ww   = w0 - 1 + spx[gi];
        wval[gi] = (unsigned)ww < 256u;
        xcol[gi] = wval[gi] ? ww : 0;
    }
    const int  tdgr  = 528 + tpx * 8 + (g ^ (tpx & 7));
    const int  tww   = w0 - 1 + tpx;
    const bool twval = ((unsigned)tww < 256u) && (tid < 32);
    const int  txcol = ((unsigned)tww < 256u) ? tww : 0;

    // b-read byte offset within slot, per (s,kw), pixel p = ni*16+col+kw
    int boff[2][3];
#pragma unroll
    for (int s = 0; s < 2; ++s)
#pragma unroll
        for (int kw = 0; kw < 3; ++kw) {
            int p = col + kw;
            boff[s][kw] = p * 128 + (((s * 4 + row4) ^ (p & 7)) << 4);
        }

    // ---- prologue: stage L = 0..3 (slots 0..3), 2112 granules ----
#pragma unroll
    for (int r = 0; r < 9; ++r) {
        int j = r * 256 + tid;
        bool act = (r < 8) || (tid < 64);
        if (act) {
            int L  = (j >= 1584) ? 3 : (j >= 1056) ? 2 : (j >= 528) ? 1 : 0;
            int jr = j - L * 528;
            int px = jr >> 3;
            int hh = h0 - 1 + L;
            int ww = w0 - 1 + px;
            bool v = ((unsigned)hh < 256u) & ((unsigned)ww < 256u);
            const float* p = xn + (size_t)ci0 * 65536 +
                             (size_t)(v ? hh : 0) * 256 + (v ? ww : 0);
            float sv[8];
#pragma unroll
            for (int e = 0; e < 8; ++e) {
                float val = p[(size_t)e * 65536];
                sv[e] = v ? val : 0.f;
            }
            uint4 wd = pack8(sv);
            *reinterpret_cast<uint4*>(
                lb + (L * 528 + px * 8 + (g ^ (px & 7))) * 16) = wd;
        }
    }
    __syncthreads();

    f32x4 acc[4][4];
#pragma unroll
    for (int mi = 0; mi < 4; ++mi)
#pragma unroll
        for (int ni = 0; ni < 4; ++ni) acc[mi][ni] = (f32x4){0.f, 0.f, 0.f, 0.f};

    const short8* Abase = reinterpret_cast<const short8*>(Af) + wm * 512 + lane;

    int slo = wn;    // (2c+wn)%6
    int sst = 4;     // (2c+4)%6  (stage base slot)

    for (int c = 0; c < 16; ++c) {
        const bool st = (c < 15);
        const int hh0 = h0 + 2 * c + 3;

        // ---- issue next-chunk loads (land under compute) ----
        float sv[4][8], tv[8];
        if (st) {
#pragma unroll
            for (int gi = 0; gi < 4; ++gi) {
                int hh = hh0 + srow[gi];
                bool v = wval[gi] & (hh < 256);
                const float* p = xn + (size_t)ci0 * 65536 +
                                 (size_t)(v ? hh : 0) * 256 + xcol[gi];
#pragma unroll
                for (int e = 0; e < 8; ++e) {
                    float val = p[(size_t)e * 65536];
                    sv[gi][e] = v ? val : 0.f;
                }
            }
            {
                int hh = hh0 + 1;
                bool v = twval & (hh < 256);
                const float* p = xn + (size_t)ci0 * 65536 +
                                 (size_t)(v ? hh : 0) * 256 + txcol;
#pragma unroll
                for (int e = 0; e < 8; ++e) {
                    float val = p[(size_t)e * 65536];
                    tv[e] = v ? val : 0.f;
                }
            }
        }

        // ---- compute (reads slots (2c..2c+3)%6) ----
        int sl1 = slo + 1; if (sl1 >= 6) sl1 -= 6;
        int sl2 = slo + 2; if (sl2 >= 6) sl2 -= 6;
        const int kb[3] = { slo * SLOT_B, sl1 * SLOT_B, sl2 * SLOT_B };

#pragma unroll
        for (int t = 0; t < 9; ++t) {
            const int kh = t / 3, kw = t % 3;
#pragma unroll
            for (int s = 0; s < 2; ++s) {
                short8 a0 = Abase[(t * 16 + 0 * 2 + s) * 64];
                short8 a1 = Abase[(t * 16 + 1 * 2 + s) * 64];
                short8 a2 = Abase[(t * 16 + 2 * 2 + s) * 64];
                short8 a3 = Abase[(t * 16 + 3 * 2 + s) * 64];
#pragma unroll
                for (int ni = 0; ni < 4; ++ni) {
                    short8 b = *reinterpret_cast<const short8*>(
                        lb + kb[kh] + ni * 2048 + boff[s][kw]);
                    acc[0][ni] = __builtin_amdgcn_mfma_f32_16x16x32_bf16(
                        a0, b, acc[0][ni], 0, 0, 0);
                    acc[1][ni] = __builtin_amdgcn_mfma_f32_16x16x32_bf16(
                        a1, b, acc[1][ni], 0, 0, 0);
                    acc[2][ni] = __builtin_amdgcn_mfma_f32_16x16x32_bf16(
                        a2, b, acc[2][ni], 0, 0, 0);
                    acc[3][ni] = __builtin_amdgcn_mfma_f32_16x16x32_bf16(
                        a3, b, acc[3][ni], 0, 0, 0);
                }
            }
        }

        // ---- pack + write-late (slots (2c+4,2c+5)%6, disjoint from reads) ----
        if (st) {
            const int dbase = sst * SLOT_B;
#pragma unroll
            for (int gi = 0; gi < 4; ++gi) {
                uint4 wd = pack8(sv[gi]);
                *reinterpret_cast<uint4*>(lb + dbase + dgr[gi] * 16) = wd;
            }
            if (tid < 32) {
                uint4 wd = pack8(tv);
                *reinterpret_cast<uint4*>(lb + dbase + tdgr * 16) = wd;
            }
        }
        __syncthreads();

        // ---- store output rows (drains under next chunk's compute) ----
        const int rr = h0 + 2 * c + wn;
        const size_t ob = (size_t)n * CH_OUT * 65536 + (size_t)rr * 256 + w0;
#pragma unroll
        for (int mi = 0; mi < 4; ++mi)
#pragma unroll
            for (int reg = 0; reg < 4; ++reg) {
                int co = wm * 64 + mi * 16 + row4 * 4 + reg;
                float* op = out + ob + (size_t)co * 65536;
#pragma unroll
                for (int ni = 0; ni < 4; ++ni) op[ni * 16 + col] = acc[mi][ni][reg];
            }
#pragma unroll
        for (int mi = 0; mi < 4; ++mi)
#pragma unroll
            for (int ni = 0; ni < 4; ++ni) acc[mi][ni] = (f32x4){0.f, 0.f, 0.f, 0.f};

        slo += 2; if (slo >= 6) slo -= 6;
        sst += 2; if (sst >= 6) sst -= 6;
    }
}

extern "C" void kernel_launch(void* const* d_in, const int* in_sizes, int n_in,
                              void* d_out, int out_size, void* d_ws, size_t ws_size,
                              hipStream_t stream) {
    const float* x  = (const float*)d_in[0];
    const float* Wh = (const float*)d_in[1];
    const float* Mh = (const float*)d_in[2];
    float* out = (float*)d_out;
    uint32_t* Af = (uint32_t*)d_ws;   // 147,456 B of A fragments

    nac_prep<<<36, 256, 0, stream>>>(Wh, Mh, Af);
    nac_conv<<<512, 256, 0, stream>>>(x, Af, out);
}

// Round 5
// 516.537 us; speedup vs baseline: 1.4326x; 1.4326x over previous
//
#include <hip/hip_runtime.h>
#include <hip/hip_bf16.h>
#include <stdint.h>

// ConvNACCell: out[n,co,h,w] = sum_{ci,kh,kw} x[n,ci,h+kh-1,w+kw-1] * W[co,ci,kh,kw]
// W = tanh(W_hat)*sigmoid(M_hat). Two pass:
//   1) convert x fp32 NCHW -> bf16 NHWC in ws (C=64 -> one pixel = 128B granule)
//   2) conv: mfma_f32_32x32x16_bf16; B-fragments read DIRECTLY from global NHWC
//      (16B contiguous per lane, L1/L2-hot), A staged in LDS via global_load_lds
//      in two 36.9KB s-phases. No x staging, nothing held in regs across MFMAs.

#define CH_IN  64
#define CH_OUT 128
#define HW     256

typedef __attribute__((ext_vector_type(8)))  short short8;   // 8 bf16 = 4 VGPR
typedef __attribute__((ext_vector_type(16))) float f32x16;   // 32x32 acc
typedef __attribute__((ext_vector_type(4)))  float f32x4;

// ws layout (bytes): A-frag table [0, 147456), xb bf16 NHWC [147456, +134217728)
#define XB_BYTE  147456u
#define WS_NEED  (147456ull + 134217728ull)

static __device__ __forceinline__ uint32_t pack_bf16(float a, float b) {
    uint32_t ua = __builtin_bit_cast(uint32_t, a);
    uint32_t ub = __builtin_bit_cast(uint32_t, b);
    ua = (ua + 0x7FFFu + ((ua >> 16) & 1u)) >> 16;
    ub = (ub + 0x7FFFu + ((ub >> 16) & 1u));
    return (ua & 0xFFFFu) | (ub & 0xFFFF0000u);
}

// ---------------------------------------------------------------------------
// Prep (32x32x16 layout): frag[t][ms(4)][s(4)][lane] (16B each):
//   elem j = A[co = ms*32 + (lane&31)][ci = s*16 + (lane>>5)*8 + j], tap t.
// 9*4*4*64*16B = 147,456 B.
// ---------------------------------------------------------------------------
__global__ void __launch_bounds__(256) nac_prep32(const float* __restrict__ Wh,
                                                  const float* __restrict__ Mh,
                                                  uint32_t* __restrict__ Af) {
    int f = blockIdx.x * 256 + threadIdx.x;   // 0..9215
    if (f >= 9 * 4 * 4 * 64) return;
    int lane = f & 63;
    int s    = (f >> 6) & 3;
    int ms   = (f >> 8) & 3;
    int t    = f >> 10;
    int co   = ms * 32 + (lane & 31);
    int ci0  = s * 16 + ((lane >> 5) << 3);

    uint32_t pk[4];
#pragma unroll
    for (int j2 = 0; j2 < 4; ++j2) {
        int ci = ci0 + 2 * j2;
        int k0 = ci * 9 + t;
        int k1 = k0 + 9;
        float w0 = tanhf(Wh[co * 576 + k0]);
        float m0 = Mh[co * 576 + k0];
        float w1 = tanhf(Wh[co * 576 + k1]);
        float m1 = Mh[co * 576 + k1];
        float v0 = w0 * (1.0f / (1.0f + expf(-m0)));
        float v1 = w1 * (1.0f / (1.0f + expf(-m1)));
        pk[j2] = pack_bf16(v0, v1);
    }
    int fragidx = ((t * 4 + ms) * 4 + s) * 64 + lane;
    reinterpret_cast<uint4*>(Af)[fragidx] = make_uint4(pk[0], pk[1], pk[2], pk[3]);
}

// Prep (16x16x32 layout) for the fallback path only.
__global__ void __launch_bounds__(256) nac_prep16(const float* __restrict__ Wh,
                                                  const float* __restrict__ Mh,
                                                  uint32_t* __restrict__ Af) {
    int f = blockIdx.x * 256 + threadIdx.x;
    if (f >= 9 * 8 * 2 * 64) return;
    int lane = f & 63;
    int s    = (f >> 6) & 1;
    int ms   = (f >> 7) & 7;
    int t    = f >> 10;
    int co   = ms * 16 + (lane & 15);
    int ci0  = s * 32 + ((lane >> 4) << 3);
    uint32_t pk[4];
#pragma unroll
    for (int j2 = 0; j2 < 4; ++j2) {
        int ci = ci0 + 2 * j2;
        int k0 = ci * 9 + t;
        int k1 = k0 + 9;
        float w0 = tanhf(Wh[co * 576 + k0]);
        float m0 = Mh[co * 576 + k0];
        float w1 = tanhf(Wh[co * 576 + k1]);
        float m1 = Mh[co * 576 + k1];
        float v0 = w0 * (1.0f / (1.0f + expf(-m0)));
        float v1 = w1 * (1.0f / (1.0f + expf(-m1)));
        pk[j2] = pack_bf16(v0, v1);
    }
    int fragidx = ((t * 8 + ms) * 2 + s) * 64 + lane;
    reinterpret_cast<uint4*>(Af)[fragidx] = make_uint4(pk[0], pk[1], pk[2], pk[3]);
}

// ---------------------------------------------------------------------------
// Convert: x [16,64,256,256] fp32 NCHW -> xb [16,256,256,64] bf16 NHWC.
// ---------------------------------------------------------------------------
__global__ void __launch_bounds__(256) nac_convert(const float* __restrict__ x,
                                                   uint32_t* __restrict__ xb) {
    int bid = blockIdx.x;            // 4096
    int h   = bid & 255;
    int n   = bid >> 8;
    int px  = threadIdx.x;
    const float* xr = x + ((size_t)n * CH_IN * HW + h) * HW + px;
    uint32_t* orow = xb + ((size_t)(n * HW + h) * HW + px) * 32;
#pragma unroll
    for (int g = 0; g < 8; ++g) {
        float v0 = xr[(size_t)(g * 8 + 0) * HW * HW];
        float v1 = xr[(size_t)(g * 8 + 1) * HW * HW];
        float v2 = xr[(size_t)(g * 8 + 2) * HW * HW];
        float v3 = xr[(size_t)(g * 8 + 3) * HW * HW];
        float v4 = xr[(size_t)(g * 8 + 4) * HW * HW];
        float v5 = xr[(size_t)(g * 8 + 5) * HW * HW];
        float v6 = xr[(size_t)(g * 8 + 6) * HW * HW];
        float v7 = xr[(size_t)(g * 8 + 7) * HW * HW];
        uint4 wd;
        wd.x = pack_bf16(v0, v1); wd.y = pack_bf16(v2, v3);
        wd.z = pack_bf16(v4, v5); wd.w = pack_bf16(v6, v7);
        *reinterpret_cast<uint4*>(orow + g * 4) = wd;
    }
}

// ---------------------------------------------------------------------------
// Conv (direct-B). Block = 64co x 4h x 64w; 4 waves (wn = output row).
// Wave = 64co(2 mi-tiles) x 64px(2 ni-tiles), acc 4 x f32x16 = 64 AGPR.
// Two s-phases (ci 0..31, 32..63): stage A (36 frags = 36.9KB) via
// global_load_lds, barrier, 72 MFMA/wave reading B straight from global.
// Grid 8192 = 2 cosplit x 64 ht x 4 wt x 16 n (cosplit = idx LSB: the two
// co-halves of a tile run adjacently -> xb read hits L2 twice).
// ---------------------------------------------------------------------------
__global__ void __launch_bounds__(256, 4)
nac_convd(const uint32_t* __restrict__ xb, const uint32_t* __restrict__ Af,
          float* __restrict__ out) {
    __shared__ __align__(1024) uint32_t al[36 * 256];   // 36,864 B

    unsigned bid = blockIdx.x;
    unsigned idx = (bid & 7u) * 1024u + (bid >> 3);   // bijective XCD swizzle
    const int cosplit = idx & 1;
    const int ht = (idx >> 1) & 63;
    const int wt = (idx >> 7) & 3;
    const int n  = idx >> 9;
    const int h0 = ht * 4;
    const int w0 = wt * 64;

    const int tid   = threadIdx.x;
    const int lane  = tid & 63;
    const int wv    = tid >> 6;      // wave = output row wn
    const int col32 = lane & 31;
    const int hi    = lane >> 5;
    const int cib   = hi * 16;       // byte offset of (lane>>5)*8 bf16

    const char* xbb = reinterpret_cast<const char*>(xb) + ((size_t)n << 23); // n*256*256*128
    const char* lb  = reinterpret_cast<const char*>(al);

    f32x16 acc[2][2];
#pragma unroll
    for (int mi = 0; mi < 2; ++mi)
#pragma unroll
        for (int ni = 0; ni < 2; ++ni)
#pragma unroll
            for (int r = 0; r < 16; ++r) acc[mi][ni][r] = 0.f;

    const short8 zero8 = (short8){0, 0, 0, 0, 0, 0, 0, 0};

#pragma unroll
    for (int ph = 0; ph < 2; ++ph) {
        if (ph) __syncthreads();     // phase-0 LDS reads complete before restage

        // ---- stage A: wave wv stages local frags f = wv*9 .. wv*9+8 ----
#pragma unroll
        for (int i = 0; i < 9; ++i) {
            const int f  = wv * 9 + i;            // t = f>>2, mi = (f>>1)&1, sl = f&1
            const int t  = f >> 2;
            const int mi = (f >> 1) & 1;
            const int sl = f & 1;
            const int gidx = ((t * 4 + (cosplit * 2 + mi)) * 4 + (ph * 2 + sl));
            const uint32_t* src = Af + gidx * 256 + lane * 4;
            __builtin_amdgcn_global_load_lds(
                (const __attribute__((address_space(1))) uint32_t*)src,
                (__attribute__((address_space(3))) uint32_t*)&al[f * 256],
                16, 0, 0);
        }
        __syncthreads();             // drains vmcnt -> staged A visible

        const int cio = ph * 64 + cib;   // byte offset of ci slice in pixel granule

#pragma unroll
        for (int t = 0; t < 9; ++t) {
            const int kh = t / 3, kw = t % 3;
            const int hh = h0 + wv + kh - 1;         // wave-uniform
            if ((unsigned)hh < 256u) {
                const char* rp = xbb + ((size_t)hh << 15);   // hh*256*128
#pragma unroll
                for (int sl = 0; sl < 2; ++sl) {
                    short8 a0 = *reinterpret_cast<const short8*>(
                        lb + (t * 4 + 0 + sl) * 1024 + lane * 16);
                    short8 a1 = *reinterpret_cast<const short8*>(
                        lb + (t * 4 + 2 + sl) * 1024 + lane * 16);
#pragma unroll
                    for (int ni = 0; ni < 2; ++ni) {
                        const int p = w0 + ni * 32 + col32 + kw - 1;
                        short8 b;
                        if ((kw == 0 && ni == 0) || (kw == 2 && ni == 1)) {
                            const bool pv = (unsigned)p < 256u;
                            const int  pc = pv ? p : (kw == 0 ? 0 : 255);
                            b = *reinterpret_cast<const short8*>(
                                rp + ((size_t)pc << 7) + cio + sl * 32);
                            if (!pv) b = zero8;
                        } else {
                            b = *reinterpret_cast<const short8*>(
                                rp + ((size_t)p << 7) + cio + sl * 32);
                        }
                        acc[0][ni] = __builtin_amdgcn_mfma_f32_32x32x16_bf16(
                            a0, b, acc[0][ni], 0, 0, 0);
                        acc[1][ni] = __builtin_amdgcn_mfma_f32_32x32x16_bf16(
                            a1, b, acc[1][ni], 0, 0, 0);
                    }
                }
            }
        }
    }

    // ---- store. C/D 32x32: col = lane&31, row = (r&3) + 8*(r>>2) + 4*hi ----
    const int hrow = h0 + wv;
    const size_t ob = ((size_t)n * CH_OUT) * 65536 + (size_t)hrow * 256 + w0;
#pragma unroll
    for (int mi = 0; mi < 2; ++mi)
#pragma unroll
        for (int r = 0; r < 16; ++r) {
            const int co = cosplit * 64 + mi * 32 + (r & 3) + 8 * (r >> 2) + 4 * hi;
            float* op = out + ob + (size_t)co * 65536;
#pragma unroll
            for (int ni = 0; ni < 2; ++ni)
                op[ni * 32 + col32] = acc[mi][ni][r];
        }
}

// ---------------------------------------------------------------------------
// Fallback (round-1 proven kernel, 16x16x32 table) if ws too small.
// ---------------------------------------------------------------------------
__global__ void __launch_bounds__(256) nac_conv_fb(const float* __restrict__ x,
                                                   const uint32_t* __restrict__ Af,
                                                   float* __restrict__ out) {
    __shared__ uint32_t xl[8 * 272 * 4];
    unsigned bid = blockIdx.x;
    unsigned idx = (bid & 7u) * 1024u + (bid >> 3);
    int ht = idx & 127;
    int wt = (idx >> 7) & 3;
    int n  = idx >> 9;
    int h0 = ht * 2;
    int w0 = wt * 64;
    int tid = threadIdx.x;

    const float* xn = x + (size_t)n * CH_IN * HW * HW;
    for (int it = 0; it < 9; ++it) {
        int task = tid + it * 256;
        if (task < 2176) {
            int r   = task / 544;
            int rem = task - r * 544;
            int pg  = rem / 68;
            int c   = rem - pg * 68;
            int hrow = h0 - 1 + r;
            int w    = w0 - 1 + c;
            float v[8];
            if ((unsigned)hrow < 256u && (unsigned)w < 256u) {
                const float* p = xn + ((size_t)(pg * 8) * HW + hrow) * HW + w;
#pragma unroll
                for (int e = 0; e < 8; ++e) v[e] = p[(size_t)e * HW * HW];
            } else {
#pragma unroll
                for (int e = 0; e < 8; ++e) v[e] = 0.0f;
            }
            uint4 wd;
            wd.x = pack_bf16(v[0], v[1]);
            wd.y = pack_bf16(v[2], v[3]);
            wd.z = pack_bf16(v[4], v[5]);
            wd.w = pack_bf16(v[6], v[7]);
            *reinterpret_cast<uint4*>(&xl[(pg * 272 + r * 68 + c) * 4]) = wd;
        }
    }
    __syncthreads();

    int lane = tid & 63;
    int wv   = tid >> 6;
    int wm   = wv >> 1;
    int wn   = wv & 1;
    int row4 = lane >> 4;
    int col  = lane & 15;

    f32x4 acc[4][4];
#pragma unroll
    for (int mi = 0; mi < 4; ++mi)
#pragma unroll
        for (int ni = 0; ni < 4; ++ni) acc[mi][ni] = (f32x4){0.f, 0.f, 0.f, 0.f};

    const short8* Afr = reinterpret_cast<const short8*>(Af);
    for (int t = 0; t < 9; ++t) {
        int kh = t / 3, kw = t % 3;
        short8 a[2][4];
#pragma unroll
        for (int s = 0; s < 2; ++s)
#pragma unroll
            for (int mi = 0; mi < 4; ++mi)
                a[s][mi] = Afr[((t * 8 + (wm * 4 + mi)) * 2 + s) * 64 + lane];
#pragma unroll
        for (int s = 0; s < 2; ++s) {
            short8 b[4];
#pragma unroll
            for (int ni = 0; ni < 4; ++ni) {
                int pg = s * 4 + row4;
                int pp = (wn + kh) * 68 + ni * 16 + col + kw;
                b[ni] = *reinterpret_cast<const short8*>(&xl[(pg * 272 + pp) * 4]);
            }
#pragma unroll
            for (int mi = 0; mi < 4; ++mi)
#pragma unroll
                for (int ni = 0; ni < 4; ++ni)
                    acc[mi][ni] = __builtin_amdgcn_mfma_f32_16x16x32_bf16(
                        a[s][mi], b[ni], acc[mi][ni], 0, 0, 0);
        }
    }

#pragma unroll
    for (int mi = 0; mi < 4; ++mi) {
#pragma unroll
        for (int reg = 0; reg < 4; ++reg) {
            int co = wm * 64 + mi * 16 + row4 * 4 + reg;
            float* op = out + (((size_t)n * CH_OUT + co) * HW + (h0 + wn)) * HW + w0;
#pragma unroll
            for (int ni = 0; ni < 4; ++ni) op[ni * 16 + col] = acc[mi][ni][reg];
        }
    }
}

extern "C" void kernel_launch(void* const* d_in, const int* in_sizes, int n_in,
                              void* d_out, int out_size, void* d_ws, size_t ws_size,
                              hipStream_t stream) {
    const float* x  = (const float*)d_in[0];
    const float* Wh = (const float*)d_in[1];
    const float* Mh = (const float*)d_in[2];
    float* out = (float*)d_out;
    uint32_t* ws32 = (uint32_t*)d_ws;
    const uint32_t* Af = ws32;
    uint32_t* xbuf = ws32 + XB_BYTE / 4;

    if (ws_size >= WS_NEED) {
        nac_prep32<<<36, 256, 0, stream>>>(Wh, Mh, ws32);
        nac_convert<<<4096, 256, 0, stream>>>(x, xbuf);
        nac_convd<<<8192, 256, 0, stream>>>(xbuf, Af, out);
    } else {
        nac_prep16<<<36, 256, 0, stream>>>(Wh, Mh, ws32);
        nac_conv_fb<<<8192, 256, 0, stream>>>(x, Af, out);
    }
}

// Round 6
// 325.758 us; speedup vs baseline: 2.2715x; 1.5856x over previous
//
#include <hip/hip_runtime.h>
#include <hip/hip_bf16.h>
#include <stdint.h>

// ConvNACCell: out[n,co,h,w] = sum_{ci,kh,kw} x[n,ci,h+kh-1,w+kw-1] * W[co,ci,kh,kw]
// W = tanh(W_hat)*sigmoid(M_hat). Implicit GEMM, mfma_f32_16x16x32_bf16.
// Pass 1: x fp32 NCHW -> bf16 NHWC (ws). Pass 2: conv, x staged via
// global_load_lds into a 10-slot row ring (4-row chunks, issue-early DMA),
// A staged once per block (co-half) into LDS. Nothing held in regs across
// the MFMA section except acc (AGPR) + one halo uint4 on wave 0.

#define CH_IN  64
#define CH_OUT 128
#define HW     256

typedef __attribute__((ext_vector_type(8))) short short8;   // 8 bf16
typedef __attribute__((ext_vector_type(4))) float f32x4;

// ws layout (bytes)
#define ZP_BYTE  147456u
#define XB_BYTE  147712u
#define WS_NEED  (147712ull + 134217728ull)

// conv3 LDS layout (bytes)
#define RING_B   81920        // 10 slots * 8192 (512 granules of 16B: px 0..63)
#define HALO_B   2560         // 10 slots * 256  (px 64,65 x 8 granules)
#define ABASE_B  84480        // RING_B + HALO_B
#define LDS_U32  39552        // 158,208 B total

static __device__ __forceinline__ uint32_t pack_bf16(float a, float b) {
    uint32_t ua = __builtin_bit_cast(uint32_t, a);
    uint32_t ub = __builtin_bit_cast(uint32_t, b);
    ua = (ua + 0x7FFFu + ((ua >> 16) & 1u)) >> 16;
    ub = (ub + 0x7FFFu + ((ub >> 16) & 1u));
    return (ua & 0xFFFFu) | (ub & 0xFFFF0000u);
}

// ---------------------------------------------------------------------------
// Prep: 16x16x32 A-fragment table + zero page.
//   frag[t][ms(8)][s(2)][lane]: elem j = A[co = ms*16 + (lane&15)]
//                                        [ci = s*32 + (lane>>4)*8 + j], tap t.
// ---------------------------------------------------------------------------
__global__ void __launch_bounds__(256) nac_prep16(const float* __restrict__ Wh,
                                                  const float* __restrict__ Mh,
                                                  uint32_t* __restrict__ ws32) {
    if (blockIdx.x == 0 && threadIdx.x < 64) ws32[ZP_BYTE / 4 + threadIdx.x] = 0;

    int f = blockIdx.x * 256 + threadIdx.x;   // 0..9215
    if (f >= 9 * 8 * 2 * 64) return;
    int lane = f & 63;
    int s    = (f >> 6) & 1;
    int ms   = (f >> 7) & 7;
    int t    = f >> 10;
    int co   = ms * 16 + (lane & 15);
    int ci0  = s * 32 + ((lane >> 4) << 3);

    uint32_t pk[4];
#pragma unroll
    for (int j2 = 0; j2 < 4; ++j2) {
        int ci = ci0 + 2 * j2;
        int k0 = ci * 9 + t;
        int k1 = k0 + 9;
        float w0 = tanhf(Wh[co * 576 + k0]);
        float m0 = Mh[co * 576 + k0];
        float w1 = tanhf(Wh[co * 576 + k1]);
        float m1 = Mh[co * 576 + k1];
        float v0 = w0 * (1.0f / (1.0f + expf(-m0)));
        float v1 = w1 * (1.0f / (1.0f + expf(-m1)));
        pk[j2] = pack_bf16(v0, v1);
    }
    int fragidx = ((t * 8 + ms) * 2 + s) * 64 + lane;
    reinterpret_cast<uint4*>(ws32)[fragidx] = make_uint4(pk[0], pk[1], pk[2], pk[3]);
}

// ---------------------------------------------------------------------------
// Convert: x [16,64,256,256] fp32 NCHW -> xb [16,256,256,64] bf16 NHWC.
// ---------------------------------------------------------------------------
__global__ void __launch_bounds__(256) nac_convert(const float* __restrict__ x,
                                                   uint32_t* __restrict__ xb) {
    int bid = blockIdx.x;            // 4096
    int h   = bid & 255;
    int n   = bid >> 8;
    int px  = threadIdx.x;
    const float* xr = x + ((size_t)n * CH_IN * HW + h) * HW + px;
    uint32_t* orow = xb + ((size_t)(n * HW + h) * HW + px) * 32;
#pragma unroll
    for (int g = 0; g < 8; ++g) {
        float v0 = xr[(size_t)(g * 8 + 0) * HW * HW];
        float v1 = xr[(size_t)(g * 8 + 1) * HW * HW];
        float v2 = xr[(size_t)(g * 8 + 2) * HW * HW];
        float v3 = xr[(size_t)(g * 8 + 3) * HW * HW];
        float v4 = xr[(size_t)(g * 8 + 4) * HW * HW];
        float v5 = xr[(size_t)(g * 8 + 5) * HW * HW];
        float v6 = xr[(size_t)(g * 8 + 6) * HW * HW];
        float v7 = xr[(size_t)(g * 8 + 7) * HW * HW];
        uint4 wd;
        wd.x = pack_bf16(v0, v1); wd.y = pack_bf16(v2, v3);
        wd.z = pack_bf16(v4, v5); wd.w = pack_bf16(v6, v7);
        *reinterpret_cast<uint4*>(orow + g * 4) = wd;
    }
}

// ---------------------------------------------------------------------------
// Conv. Block = 64co (cosplit) x 16h x 64w; 4 waves, wave = 1 output row.
// x ring: slot L%10 holds input row hh = h0+L-1, px 0..63 (ww = w0-1+px),
//   granule (px,g) stores ci-octet g^(px&7) (read applies same XOR -> no
//   bank conflicts, measured 0 in R3). Halo strip: px 64,65 per slot.
// Chunk c: computes rows 4c..4c+3 (reads L 4c..4c+5), DMA-stages L 4c+6..4c+9.
// A: co-half frag table (72 frags) staged once at ABASE_B.
// ---------------------------------------------------------------------------
__global__ void __launch_bounds__(256)
nac_conv3(const uint32_t* __restrict__ xb, const uint32_t* __restrict__ Af,
          float* __restrict__ out, const uint32_t* __restrict__ zp) {
    __shared__ __align__(1024) uint32_t lds[LDS_U32];

    unsigned bid = blockIdx.x;
    unsigned idx = (bid & 7u) * 256u + (bid >> 3);   // bijective XCD swizzle
    const int cosplit = idx & 1;
    const int ht = (idx >> 1) & 15;
    const int wt = (idx >> 5) & 3;
    const int n  = idx >> 7;
    const int h0 = ht * 16, w0 = wt * 64;

    const int tid  = threadIdx.x;
    const int lane = tid & 63;
    const int wv   = tid >> 6;
    const int col  = lane & 15;
    const int row4 = lane >> 4;

    const char* xbn = reinterpret_cast<const char*>(xb) + ((size_t)n << 23);
    char* lb = reinterpret_cast<char*>(lds);

    // ---- stage A: 72 frags = 4608 granules = 18 passes ----
#pragma unroll
    for (int i = 0; i < 18; ++i) {
        const int fa = i * 4 + wv;            // frag 0..71 (wave-uniform)
        const int t  = fa >> 3;
        const int r8 = fa & 7;
        const int mi = r8 >> 1;
        const int s  = r8 & 1;
        const int gfrag = (t * 8 + cosplit * 4 + mi) * 2 + s;
        const uint32_t* src = Af + (size_t)(gfrag * 64 + lane) * 4;
        __builtin_amdgcn_global_load_lds(
            (const __attribute__((address_space(1))) uint32_t*)src,
            (__attribute__((address_space(3))) uint32_t*)
                (lds + (ABASE_B + (i * 256 + (tid & ~63)) * 16) / 4),
            16, 0, 0);
    }

    // ---- x stage helper: 4 rows (2048 granules = 8 passes), slots never wrap
    auto stage4 = [&](int slotbase, int hhbase) {
#pragma unroll
        for (int i = 0; i < 8; ++i) {
            const int row = i >> 1;                  // pass-uniform
            const int jr  = (i & 1) * 256 + tid;     // 0..511 within row
            const int px  = jr >> 3;
            const int g   = jr & 7;
            int sl = slotbase + row; if (sl >= 10) sl -= 10;
            const int hh = hhbase + row;
            const int ww = w0 - 1 + px;
            const bool v = ((unsigned)hh < 256u) & ((unsigned)ww < 256u);
            const int hhc = v ? hh : 0;
            const int wwc = v ? ww : 0;
            const uint32_t* src = v
                ? (const uint32_t*)(xbn + ((size_t)(hhc * 256 + wwc) << 7)
                                        + ((g ^ (px & 7)) << 4))
                : zp;
            __builtin_amdgcn_global_load_lds(
                (const __attribute__((address_space(1))) uint32_t*)src,
                (__attribute__((address_space(3))) uint32_t*)
                    (lds + (sl * 8192 + ((i & 1) * 256 + (tid & ~63)) * 16) / 4),
                16, 0, 0);
        }
    };

    // ---- prologue: x rows L0..3 and L4..5, halo L0..5, then barrier ----
    stage4(0, h0 - 1);
#pragma unroll
    for (int i = 0; i < 4; ++i) {                    // rows L4,L5
        const int row = i >> 1;
        const int jr  = (i & 1) * 256 + tid;
        const int px  = jr >> 3;
        const int g   = jr & 7;
        const int sl  = 4 + row;
        const int hh  = h0 + 3 + row;
        const int ww  = w0 - 1 + px;
        const bool v  = ((unsigned)hh < 256u) & ((unsigned)ww < 256u);
        const int hhc = v ? hh : 0;
        const int wwc = v ? ww : 0;
        const uint32_t* src = v
            ? (const uint32_t*)(xbn + ((size_t)(hhc * 256 + wwc) << 7)
                                    + ((g ^ (px & 7)) << 4))
            : zp;
        __builtin_amdgcn_global_load_lds(
            (const __attribute__((address_space(1))) uint32_t*)src,
            (__attribute__((address_space(3))) uint32_t*)
                (lds + (sl * 8192 + ((i & 1) * 256 + (tid & ~63)) * 16) / 4),
            16, 0, 0);
    }
    if (tid < 96) {                                  // halo px 64,65 for L0..5
        const int row = tid >> 4;
        const int hx  = tid & 15;
        const int px  = 64 + (hx >> 3);
        const int g   = hx & 7;
        const int hh  = h0 - 1 + row;
        const int ww  = w0 - 1 + px;
        const bool v  = ((unsigned)hh < 256u) & ((unsigned)ww < 256u);
        const uint32_t* src = v
            ? (const uint32_t*)(xbn + ((size_t)(hh * 256 + ww) << 7)
                                    + ((g ^ (px & 7)) << 4))
            : zp;
        uint4 hv = *reinterpret_cast<const uint4*>(src);
        *reinterpret_cast<uint4*>(lb + RING_B + row * 256 + hx * 16) = hv;
    }
    __syncthreads();

    // ---- per-lane read-offset precompute ----
    int base[2][3];
    bool sel3[3];
#pragma unroll
    for (int s = 0; s < 2; ++s)
#pragma unroll
        for (int kw = 0; kw < 3; ++kw) {
            const int p = col + kw;
            base[s][kw] = p * 128 + (((s * 4 + row4) ^ (p & 7)) << 4);
        }
#pragma unroll
    for (int kw = 0; kw < 3; ++kw) sel3[kw] = (48 + col + kw) < 64;

    int slR = 0, sstW = 6;
    for (int c = 0; c < 4; ++c) {
        const bool st = (c < 3);
        uint4 hv;

        // ---- issue next-group DMA + halo loads (land under compute) ----
        if (st) {
            stage4(sstW, h0 + 4 * c + 5);
            if (tid < 64) {
                const int row = tid >> 4;
                const int hx  = tid & 15;
                const int px  = 64 + (hx >> 3);
                const int g   = hx & 7;
                const int hh  = h0 + 4 * c + 5 + row;
                const int ww  = w0 - 1 + px;
                const bool v  = ((unsigned)hh < 256u) & ((unsigned)ww < 256u);
                const uint32_t* src = v
                    ? (const uint32_t*)(xbn + ((size_t)(hh * 256 + ww) << 7)
                                            + ((g ^ (px & 7)) << 4))
                    : zp;
                hv = *reinterpret_cast<const uint4*>(src);
            }
            __builtin_amdgcn_sched_barrier(0);
        }

        // ---- compute: rows 4c..4c+3 (wave wv = row 4c+wv) ----
        f32x4 acc[4][4];
#pragma unroll
        for (int mi = 0; mi < 4; ++mi)
#pragma unroll
            for (int ni = 0; ni < 4; ++ni) acc[mi][ni] = (f32x4){0.f, 0.f, 0.f, 0.f};

        const int sb = slR + wv;
#pragma unroll
        for (int kh = 0; kh < 3; ++kh) {
            int sl = sb + kh; if (sl >= 10) sl -= 10;
            const int mb = sl * 8192;
            const int hb = RING_B + sl * 256;
#pragma unroll
            for (int kw = 0; kw < 3; ++kw) {
                const int t = kh * 3 + kw;
                const int csel = sel3[kw] ? (mb + 6144) : (hb - 2048);
#pragma unroll
                for (int s = 0; s < 2; ++s) {
                    const int ab = ABASE_B + (t * 8 + s) * 1024 + lane * 16;
                    short8 a0 = *reinterpret_cast<const short8*>(lb + ab);
                    short8 a1 = *reinterpret_cast<const short8*>(lb + ab + 2048);
                    short8 a2 = *reinterpret_cast<const short8*>(lb + ab + 4096);
                    short8 a3 = *reinterpret_cast<const short8*>(lb + ab + 6144);
                    const int bb = mb + base[s][kw];
                    short8 b0 = *reinterpret_cast<const short8*>(lb + bb);
                    short8 b1 = *reinterpret_cast<const short8*>(lb + bb + 2048);
                    short8 b2 = *reinterpret_cast<const short8*>(lb + bb + 4096);
                    short8 b3 = *reinterpret_cast<const short8*>(lb + csel + base[s][kw]);
                    acc[0][0] = __builtin_amdgcn_mfma_f32_16x16x32_bf16(a0, b0, acc[0][0], 0, 0, 0);
                    acc[1][0] = __builtin_amdgcn_mfma_f32_16x16x32_bf16(a1, b0, acc[1][0], 0, 0, 0);
                    acc[2][0] = __builtin_amdgcn_mfma_f32_16x16x32_bf16(a2, b0, acc[2][0], 0, 0, 0);
                    acc[3][0] = __builtin_amdgcn_mfma_f32_16x16x32_bf16(a3, b0, acc[3][0], 0, 0, 0);
                    acc[0][1] = __builtin_amdgcn_mfma_f32_16x16x32_bf16(a0, b1, acc[0][1], 0, 0, 0);
                    acc[1][1] = __builtin_amdgcn_mfma_f32_16x16x32_bf16(a1, b1, acc[1][1], 0, 0, 0);
                    acc[2][1] = __builtin_amdgcn_mfma_f32_16x16x32_bf16(a2, b1, acc[2][1], 0, 0, 0);
                    acc[3][1] = __builtin_amdgcn_mfma_f32_16x16x32_bf16(a3, b1, acc[3][1], 0, 0, 0);
                    acc[0][2] = __builtin_amdgcn_mfma_f32_16x16x32_bf16(a0, b2, acc[0][2], 0, 0, 0);
                    acc[1][2] = __builtin_amdgcn_mfma_f32_16x16x32_bf16(a1, b2, acc[1][2], 0, 0, 0);
                    acc[2][2] = __builtin_amdgcn_mfma_f32_16x16x32_bf16(a2, b2, acc[2][2], 0, 0, 0);
                    acc[3][2] = __builtin_amdgcn_mfma_f32_16x16x32_bf16(a3, b2, acc[3][2], 0, 0, 0);
                    acc[0][3] = __builtin_amdgcn_mfma_f32_16x16x32_bf16(a0, b3, acc[0][3], 0, 0, 0);
                    acc[1][3] = __builtin_amdgcn_mfma_f32_16x16x32_bf16(a1, b3, acc[1][3], 0, 0, 0);
                    acc[2][3] = __builtin_amdgcn_mfma_f32_16x16x32_bf16(a2, b3, acc[2][3], 0, 0, 0);
                    acc[3][3] = __builtin_amdgcn_mfma_f32_16x16x32_bf16(a3, b3, acc[3][3], 0, 0, 0);
                }
            }
        }

        // ---- halo write-late (slots sstW..sstW+3, disjoint from reads) ----
        if (st && tid < 64) {
            const int row = tid >> 4;
            const int hx  = tid & 15;
            int sl = sstW + row; if (sl >= 10) sl -= 10;
            *reinterpret_cast<uint4*>(lb + RING_B + sl * 256 + hx * 16) = hv;
        }
        __syncthreads();

        // ---- store row 4c+wv (drains under next chunk's compute) ----
        const int rr = h0 + 4 * c + wv;
        const size_t ob = (size_t)n * CH_OUT * 65536 + (size_t)rr * 256 + w0;
#pragma unroll
        for (int mi = 0; mi < 4; ++mi)
#pragma unroll
            for (int reg = 0; reg < 4; ++reg) {
                const int co = cosplit * 64 + mi * 16 + row4 * 4 + reg;
                float* op = out + ob + (size_t)co * 65536;
#pragma unroll
                for (int ni = 0; ni < 4; ++ni) op[ni * 16 + col] = acc[mi][ni][reg];
            }

        slR += 4;  if (slR >= 10)  slR -= 10;
        sstW += 4; if (sstW >= 10) sstW -= 10;
    }
}

// ---------------------------------------------------------------------------
// Fallback (round-1 proven kernel) if ws too small.
// ---------------------------------------------------------------------------
__global__ void __launch_bounds__(256) nac_conv_fb(const float* __restrict__ x,
                                                   const uint32_t* __restrict__ Af,
                                                   float* __restrict__ out) {
    __shared__ uint32_t xl[8 * 272 * 4];
    unsigned bid = blockIdx.x;
    unsigned idx = (bid & 7u) * 1024u + (bid >> 3);
    int ht = idx & 127;
    int wt = (idx >> 7) & 3;
    int n  = idx >> 9;
    int h0 = ht * 2;
    int w0 = wt * 64;
    int tid = threadIdx.x;

    const float* xn = x + (size_t)n * CH_IN * HW * HW;
    for (int it = 0; it < 9; ++it) {
        int task = tid + it * 256;
        if (task < 2176) {
            int r   = task / 544;
            int rem = task - r * 544;
            int pg  = rem / 68;
            int c   = rem - pg * 68;
            int hrow = h0 - 1 + r;
            int w    = w0 - 1 + c;
            float v[8];
            if ((unsigned)hrow < 256u && (unsigned)w < 256u) {
                const float* p = xn + ((size_t)(pg * 8) * HW + hrow) * HW + w;
#pragma unroll
                for (int e = 0; e < 8; ++e) v[e] = p[(size_t)e * HW * HW];
            } else {
#pragma unroll
                for (int e = 0; e < 8; ++e) v[e] = 0.0f;
            }
            uint4 wd;
            wd.x = pack_bf16(v[0], v[1]);
            wd.y = pack_bf16(v[2], v[3]);
            wd.z = pack_bf16(v[4], v[5]);
            wd.w = pack_bf16(v[6], v[7]);
            *reinterpret_cast<uint4*>(&xl[(pg * 272 + r * 68 + c) * 4]) = wd;
        }
    }
    __syncthreads();

    int lane = tid & 63;
    int wv   = tid >> 6;
    int wm   = wv >> 1;
    int wn   = wv & 1;
    int row4 = lane >> 4;
    int col  = lane & 15;

    f32x4 acc[4][4];
#pragma unroll
    for (int mi = 0; mi < 4; ++mi)
#pragma unroll
        for (int ni = 0; ni < 4; ++ni) acc[mi][ni] = (f32x4){0.f, 0.f, 0.f, 0.f};

    const short8* Afr = reinterpret_cast<const short8*>(Af);
    for (int t = 0; t < 9; ++t) {
        int kh = t / 3, kw = t % 3;
        short8 a[2][4];
#pragma unroll
        for (int s = 0; s < 2; ++s)
#pragma unroll
            for (int mi = 0; mi < 4; ++mi)
                a[s][mi] = Afr[((t * 8 + (wm * 4 + mi)) * 2 + s) * 64 + lane];
#pragma unroll
        for (int s = 0; s < 2; ++s) {
            short8 b[4];
#pragma unroll
            for (int ni = 0; ni < 4; ++ni) {
                int pg = s * 4 + row4;
                int pp = (wn + kh) * 68 + ni * 16 + col + kw;
                b[ni] = *reinterpret_cast<const short8*>(&xl[(pg * 272 + pp) * 4]);
            }
#pragma unroll
            for (int mi = 0; mi < 4; ++mi)
#pragma unroll
                for (int ni = 0; ni < 4; ++ni)
                    acc[mi][ni] = __builtin_amdgcn_mfma_f32_16x16x32_bf16(
                        a[s][mi], b[ni], acc[mi][ni], 0, 0, 0);
        }
    }

#pragma unroll
    for (int mi = 0; mi < 4; ++mi) {
#pragma unroll
        for (int reg = 0; reg < 4; ++reg) {
            int co = wm * 64 + mi * 16 + row4 * 4 + reg;
            float* op = out + (((size_t)n * CH_OUT + co) * HW + (h0 + wn)) * HW + w0;
#pragma unroll
            for (int ni = 0; ni < 4; ++ni) op[ni * 16 + col] = acc[mi][ni][reg];
        }
    }
}

extern "C" void kernel_launch(void* const* d_in, const int* in_sizes, int n_in,
                              void* d_out, int out_size, void* d_ws, size_t ws_size,
                              hipStream_t stream) {
    const float* x  = (const float*)d_in[0];
    const float* Wh = (const float*)d_in[1];
    const float* Mh = (const float*)d_in[2];
    float* out = (float*)d_out;
    uint32_t* ws32 = (uint32_t*)d_ws;
    const uint32_t* Af = ws32;
    const uint32_t* zp = ws32 + ZP_BYTE / 4;
    uint32_t* xbuf = ws32 + XB_BYTE / 4;

    nac_prep16<<<36, 256, 0, stream>>>(Wh, Mh, ws32);
    if (ws_size >= WS_NEED) {
        nac_convert<<<4096, 256, 0, stream>>>(x, xbuf);
        nac_conv3<<<2048, 256, 0, stream>>>(xbuf, Af, out, zp);
    } else {
        nac_conv_fb<<<8192, 256, 0, stream>>>(x, Af, out);
    }
}